// Round 11
// baseline (501.832 us; speedup 1.0000x reference)
//
#include <hip/hip_runtime.h>
#include <hip/hip_bf16.h>
#include <cstddef>

// Problem constants
constexpr int NL = 2, DM = 512, DI = 1024, DS = 8, DC = 4, DTR = 32, NC = 50;
constexpr int B = 4, L = 2048;
constexpr int M = B * L;          // 8192 rows
constexpr int XZW = 2 * DI;       // 2048
constexpr int XDW = DTR + 2 * DS; // 48
constexpr int XPR = 64;           // x_proj weight rows padded to 64
constexpr int NCH = 32, CH = L / NCH; // chunked scan: 32 chunks of 64
constexpr int XSK = 8;            // split-K for x_proj

typedef __bf16 bf16_t;
typedef bf16_t bf16x8 __attribute__((ext_vector_type(8)));
typedef bf16_t bf16x4 __attribute__((ext_vector_type(4)));
typedef float f32x4 __attribute__((ext_vector_type(4)));

// async global->LDS, 16 bytes per lane
__device__ __forceinline__ void gload16(const bf16_t* g, bf16_t* l) {
    __builtin_amdgcn_global_load_lds(
        (const __attribute__((address_space(1))) void*)g,
        (__attribute__((address_space(3))) void*)l, 16, 0, 0);
}

// ---------------- embed + layer-0 LN fused ----------------------------------
__global__ __launch_bounds__(256) void embed_ln_k(const float* __restrict__ x,
                                                  const float* __restrict__ iw,
                                                  const float* __restrict__ ib,
                                                  const float* __restrict__ g,
                                                  const float* __restrict__ bvec,
                                                  float* __restrict__ h,
                                                  bf16_t* __restrict__ out) {
    int row = blockIdx.x;
    int t = threadIdx.x;
    float xv = x[row];
    float v0 = xv * iw[t] + ib[t];
    float v1 = xv * iw[t + 256] + ib[t + 256];
    h[(size_t)row * DM + t] = v0;
    h[(size_t)row * DM + t + 256] = v1;
    float s = v0 + v1, sq = v0 * v0 + v1 * v1;
    for (int o = 32; o > 0; o >>= 1) {
        s += __shfl_down(s, o);
        sq += __shfl_down(sq, o);
    }
    __shared__ float sums[8];
    if ((t & 63) == 0) { sums[t >> 6] = s; sums[4 + (t >> 6)] = sq; }
    __syncthreads();
    float tot = sums[0] + sums[1] + sums[2] + sums[3];
    float totq = sums[4] + sums[5] + sums[6] + sums[7];
    float mu = tot * (1.0f / DM);
    float var = totq * (1.0f / DM) - mu * mu;
    float rs = rsqrtf(var + 1e-5f);
    out[(size_t)row * DM + t]       = (bf16_t)((v0 - mu) * rs * g[t] + bvec[t]);
    out[(size_t)row * DM + t + 256] = (bf16_t)((v1 - mu) * rs * g[t + 256] + bvec[t + 256]);
}

// ---------------- weight fp32 -> bf16 (xp padded to 64 rows with zeros) -----
constexpr int WN1 = NL * XZW * DM / 4;
constexpr int WN2p = NL * XPR * DI / 4;
constexpr int WN3 = NL * DI * DTR / 4;
constexpr int WN4 = NL * DM * DI / 4;
constexpr int WNTp = WN1 + WN2p + WN3 + WN4;
__global__ void cvt_ws_k(const float* __restrict__ s1, const float* __restrict__ s2,
                         const float* __restrict__ s3, const float* __restrict__ s4,
                         bf16_t* __restrict__ d1, bf16_t* __restrict__ d2,
                         bf16_t* __restrict__ d3, bf16_t* __restrict__ d4) {
    int i4 = blockIdx.x * 256 + threadIdx.x;
    if (i4 >= WNTp) return;
    if (i4 < WN1) {
        float4 f = reinterpret_cast<const float4*>(s1)[i4];
        bf16x4 v;
        v[0] = (bf16_t)f.x; v[1] = (bf16_t)f.y; v[2] = (bf16_t)f.z; v[3] = (bf16_t)f.w;
        *reinterpret_cast<bf16x4*>(d1 + (size_t)i4 * 4) = v;
    } else if (i4 < WN1 + WN2p) {
        int off = i4 - WN1;
        int layer = off / (XPR * DI / 4);
        int rem = off % (XPR * DI / 4);
        int row = rem / (DI / 4);
        int c4 = rem % (DI / 4);
        bf16x4 v;
        if (row < XDW) {
            float4 f = reinterpret_cast<const float4*>(s2)[((size_t)layer * XDW + row) * (DI / 4) + c4];
            v[0] = (bf16_t)f.x; v[1] = (bf16_t)f.y; v[2] = (bf16_t)f.z; v[3] = (bf16_t)f.w;
        } else {
            v[0] = (bf16_t)0.f; v[1] = (bf16_t)0.f; v[2] = (bf16_t)0.f; v[3] = (bf16_t)0.f;
        }
        *reinterpret_cast<bf16x4*>(d2 + (size_t)off * 4) = v;
    } else if (i4 < WN1 + WN2p + WN3) {
        int off = i4 - WN1 - WN2p;
        float4 f = reinterpret_cast<const float4*>(s3)[off];
        bf16x4 v;
        v[0] = (bf16_t)f.x; v[1] = (bf16_t)f.y; v[2] = (bf16_t)f.z; v[3] = (bf16_t)f.w;
        *reinterpret_cast<bf16x4*>(d3 + (size_t)off * 4) = v;
    } else {
        int off = i4 - WN1 - WN2p - WN3;
        float4 f = reinterpret_cast<const float4*>(s4)[off];
        bf16x4 v;
        v[0] = (bf16_t)f.x; v[1] = (bf16_t)f.y; v[2] = (bf16_t)f.z; v[3] = (bf16_t)f.w;
        *reinterpret_cast<bf16x4*>(d4 + (size_t)off * 4) = v;
    }
}

// ---------------- layernorm over last dim (DM=512), bf16 output -------------
__global__ __launch_bounds__(256) void layernorm_k(const float* __restrict__ in,
                                                   const float* __restrict__ g,
                                                   const float* __restrict__ b,
                                                   bf16_t* __restrict__ out) {
    int row = blockIdx.x;
    const float* x = in + (size_t)row * DM;
    int t = threadIdx.x;
    float v0 = x[t], v1 = x[t + 256];
    float s = v0 + v1, sq = v0 * v0 + v1 * v1;
    for (int o = 32; o > 0; o >>= 1) {
        s += __shfl_down(s, o);
        sq += __shfl_down(sq, o);
    }
    __shared__ float sums[8];
    if ((t & 63) == 0) { sums[t >> 6] = s; sums[4 + (t >> 6)] = sq; }
    __syncthreads();
    float tot = sums[0] + sums[1] + sums[2] + sums[3];
    float totq = sums[4] + sums[5] + sums[6] + sums[7];
    float mu = tot * (1.0f / DM);
    float var = totq * (1.0f / DM) - mu * mu;
    float rs = rsqrtf(var + 1e-5f);
    out[(size_t)row * DM + t]       = (bf16_t)((v0 - mu) * rs * g[t] + b[t]);
    out[(size_t)row * DM + t + 256] = (bf16_t)((v1 - mu) * rs * g[t + 256] + b[t + 256]);
}

// ---------------- bf16 MFMA GEMM: C[m,n] (+)= sum_k A[m,k]*W[n,k] ----------
// global_load_lds staging, pre-swizzled source + linear LDS dest, dbuf,
// one barrier per K-step. 256 threads = 4 waves 2x2. BK = 32.
// EPI: 0 = store, 1 = accumulate (fp32), 2 = softplus(acc+bias[n])
template <int BM, int BN, int EPI, typename TC, int SK>
__global__ __launch_bounds__(256) void gemm_mfma(const bf16_t* __restrict__ A, int lda,
                                                 const bf16_t* __restrict__ W, int ldw,
                                                 const float* __restrict__ bias,
                                                 TC* __restrict__ C, int ldc,
                                                 int Nr, int K) {
    constexpr int WM = BM / 2, WN = BN / 2;
    constexpr int FM = WM / 16, FN = WN / 16;
    __shared__ __align__(16) bf16_t As[2][BM * 32];
    __shared__ __align__(16) bf16_t Ws[2][BN * 32];

    int tid = threadIdx.x;
    int m0 = blockIdx.y * BM, n0 = blockIdx.x * BN;
    int Ktot = K;
    if constexpr (SK > 1) {
        int s = blockIdx.z;
        Ktot = K / SK;
        A += (size_t)s * Ktot;
        W += (size_t)s * Ktot;
        C += (size_t)s * (size_t)(gridDim.y * BM) * ldc;
    }
    int wave = tid >> 6, lane = tid & 63;
    int wr = wave >> 1, wc = wave & 1;
    int lr = lane & 15, lk = lane >> 4;

    auto stage = [&](int k0, int buf) {
#pragma unroll
        for (int c = 0; c < BM / 64; ++c) {
            int e = tid + c * 256;
            int r = e >> 2, slot = e & 3;
            int g = slot ^ ((r >> 1) & 3);
            gload16(A + (size_t)(m0 + r) * lda + k0 + g * 8, &As[buf][e * 8]);
        }
#pragma unroll
        for (int c = 0; c < BN / 64; ++c) {
            int e = tid + c * 256;
            int r = e >> 2, slot = e & 3;
            int g = slot ^ ((r >> 1) & 3);
            gload16(W + (size_t)(n0 + r) * ldw + k0 + g * 8, &Ws[buf][e * 8]);
        }
    };

    f32x4 acc[FM][FN];
#pragma unroll
    for (int i = 0; i < FM; i++)
#pragma unroll
        for (int j = 0; j < FN; j++)
#pragma unroll
            for (int q = 0; q < 4; q++) acc[i][j][q] = 0.0f;

    stage(0, 0);
    __syncthreads();

    int nt = Ktot / 32;
    int cur = 0;
    for (int t = 0; t < nt; ++t) {
        if (t + 1 < nt) stage((t + 1) * 32, cur ^ 1);

        bf16x8 af[FM], bfr[FN];
#pragma unroll
        for (int mi = 0; mi < FM; mi++) {
            int r = wr * WM + mi * 16 + lr;
            int slot = lk ^ ((r >> 1) & 3);
            af[mi] = *reinterpret_cast<const bf16x8*>(&As[cur][r * 32 + slot * 8]);
        }
#pragma unroll
        for (int ni = 0; ni < FN; ni++) {
            int r = wc * WN + ni * 16 + lr;
            int slot = lk ^ ((r >> 1) & 3);
            bfr[ni] = *reinterpret_cast<const bf16x8*>(&Ws[cur][r * 32 + slot * 8]);
        }
#pragma unroll
        for (int mi = 0; mi < FM; mi++)
#pragma unroll
            for (int ni = 0; ni < FN; ni++)
                acc[mi][ni] = __builtin_amdgcn_mfma_f32_16x16x32_bf16(af[mi], bfr[ni], acc[mi][ni], 0, 0, 0);

        __syncthreads();
        cur ^= 1;
    }

    // epilogue: C/D layout col=lane&15, row=(lane>>4)*4+reg
#pragma unroll
    for (int mi = 0; mi < FM; mi++) {
#pragma unroll
        for (int ni = 0; ni < FN; ni++) {
            int col = n0 + wc * WN + ni * 16 + lr;
            if (col >= Nr) continue;
#pragma unroll
            for (int i = 0; i < 4; i++) {
                int row = m0 + wr * WM + mi * 16 + lk * 4 + i;
                size_t idx = (size_t)row * ldc + col;
                float v = acc[mi][ni][i];
                if constexpr (EPI == 0) {
                    C[idx] = (TC)v;
                } else if constexpr (EPI == 1) {
                    C[idx] += v;
                } else {
                    float s = v + bias[col];
                    C[idx] = (TC)((s > 20.0f) ? s : __logf(1.0f + __expf(s)));
                }
            }
        }
    }
}

// ---------------- x_proj split-K reduce (also emits bf16 dt-input copy) -----
__global__ void xproj_reduce_k(const float* __restrict__ part, float* __restrict__ xdbl,
                               bf16_t* __restrict__ xdt) {
    int idx = blockIdx.x * blockDim.x + threadIdx.x;
    if (idx >= M * XDW) return;
    int m = idx / XDW, j = idx % XDW;
    float s = 0.f;
#pragma unroll
    for (int sp = 0; sp < XSK; sp++) s += part[((size_t)sp * M + m) * 64 + j];
    xdbl[idx] = s;
    if (j < DTR) xdt[(size_t)m * DTR + j] = (bf16_t)s;
}

// ---------------- causal depthwise conv (DC=4) + SiLU, 8 channels/thread ----
__global__ __launch_bounds__(256) void conv_silu_k(const bf16_t* __restrict__ xz,
                                                   const float* __restrict__ cw,
                                                   const float* __restrict__ cb,
                                                   bf16_t* __restrict__ uc) {
    int idx = blockIdx.x * blockDim.x + threadIdx.x;   // over M*DI/8
    if (idx >= M * DI / 8) return;
    int d8 = idx % (DI / 8);
    int m = idx / (DI / 8);
    int b = m / L, l = m % L;
    int d0 = d8 * 8;

    float acc[8];
    {
        float4 c0 = *reinterpret_cast<const float4*>(cb + d0);
        float4 c1 = *reinterpret_cast<const float4*>(cb + d0 + 4);
        acc[0] = c0.x; acc[1] = c0.y; acc[2] = c0.z; acc[3] = c0.w;
        acc[4] = c1.x; acc[5] = c1.y; acc[6] = c1.z; acc[7] = c1.w;
    }
    float4 w[8];
#pragma unroll
    for (int j = 0; j < 8; j++)
        w[j] = *reinterpret_cast<const float4*>(cw + (size_t)(d0 + j) * DC);

#pragma unroll
    for (int k = 0; k < DC; k++) {
        int ls = l + k - (DC - 1);
        if (ls < 0) continue;
        bf16x8 v = *reinterpret_cast<const bf16x8*>(xz + (size_t)(b * L + ls) * XZW + d0);
        float wk[8] = {w[0].x, w[1].x, w[2].x, w[3].x, w[4].x, w[5].x, w[6].x, w[7].x};
        if (k == 1) { wk[0]=w[0].y; wk[1]=w[1].y; wk[2]=w[2].y; wk[3]=w[3].y; wk[4]=w[4].y; wk[5]=w[5].y; wk[6]=w[6].y; wk[7]=w[7].y; }
        if (k == 2) { wk[0]=w[0].z; wk[1]=w[1].z; wk[2]=w[2].z; wk[3]=w[3].z; wk[4]=w[4].z; wk[5]=w[5].z; wk[6]=w[6].z; wk[7]=w[7].z; }
        if (k == 3) { wk[0]=w[0].w; wk[1]=w[1].w; wk[2]=w[2].w; wk[3]=w[3].w; wk[4]=w[4].w; wk[5]=w[5].w; wk[6]=w[6].w; wk[7]=w[7].w; }
#pragma unroll
        for (int j = 0; j < 8; j++) acc[j] += (float)v[j] * wk[j];
    }
    bf16x8 o;
#pragma unroll
    for (int j = 0; j < 8; j++) {
        float a = acc[j];
        o[j] = (bf16_t)(a / (1.0f + __expf(-a)));
    }
    *reinterpret_cast<bf16x8*>(uc + (size_t)m * DI + d0) = o;
}

// ---------------- selective scan, 3-phase chunked ---------------------------
// hpart/aprod layout: [b][c][d][n] (coalesced float4 along d)
__global__ __launch_bounds__(256) void scan_part_k(const bf16_t* __restrict__ dt,
                                                   const bf16_t* __restrict__ uc,
                                                   const float* __restrict__ xdbl,
                                                   const float* __restrict__ A_log,
                                                   float* __restrict__ hpart,
                                                   float* __restrict__ aprod) {
    int gid = blockIdx.x * 256 + threadIdx.x;
    if (gid >= B * NCH * DI) return;
    int d = gid % DI;
    int c = (gid / DI) % NCH;
    int b = gid / (DI * NCH);
    float Av[DS];
    {
        float4 a0 = *reinterpret_cast<const float4*>(A_log + d * DS);
        float4 a1 = *reinterpret_cast<const float4*>(A_log + d * DS + 4);
        Av[0] = -__expf(a0.x); Av[1] = -__expf(a0.y); Av[2] = -__expf(a0.z); Av[3] = -__expf(a0.w);
        Av[4] = -__expf(a1.x); Av[5] = -__expf(a1.y); Av[6] = -__expf(a1.z); Av[7] = -__expf(a1.w);
    }
    float h[DS] = {};
    float ap[DS];
#pragma unroll
    for (int n = 0; n < DS; n++) ap[n] = 1.0f;
    int l0 = c * CH;
    for (int t = 0; t < CH; t++) {
        size_t row = (size_t)b * L + l0 + t;
        float dtv = (float)dt[row * DI + d];
        float uv = (float)uc[row * DI + d];
        const float4* xr4 = reinterpret_cast<const float4*>(xdbl + row * XDW + DTR);
        float4 b0 = xr4[0], b1 = xr4[1];
        float Bv[DS] = {b0.x, b0.y, b0.z, b0.w, b1.x, b1.y, b1.z, b1.w};
        float du = dtv * uv;
#pragma unroll
        for (int n = 0; n < DS; n++) {
            float dA = __expf(dtv * Av[n]);
            h[n] = dA * h[n] + du * Bv[n];
            ap[n] *= dA;
        }
    }
    size_t base = (((size_t)(b * NCH + c) * DI) + d) * DS;
    f32x4* hp4 = reinterpret_cast<f32x4*>(hpart + base);
    f32x4* ap4 = reinterpret_cast<f32x4*>(aprod + base);
    f32x4 v0, v1, w0, w1;
#pragma unroll
    for (int n = 0; n < 4; n++) { v0[n] = h[n]; v1[n] = h[n + 4]; w0[n] = ap[n]; w1[n] = ap[n + 4]; }
    hp4[0] = v0; hp4[1] = v1;
    ap4[0] = w0; ap4[1] = w1;
}

// per (b,d,n) sequential combine over chunks; hpart[c] := state BEFORE chunk c
__global__ void scan_combine_k(float* __restrict__ hpart, const float* __restrict__ aprod) {
    int gid = blockIdx.x * blockDim.x + threadIdx.x;
    if (gid >= B * DI * DS) return;
    int dn = gid & (DI * DS - 1);      // (d,n) combined: consecutive lanes coalesced
    int b = gid >> 13;
    float hrun = 0.f;
    for (int c = 0; c < NCH; c++) {
        size_t idx = ((size_t)(b * NCH + c) * DI * DS) + dn;
        float ap = aprod[idx];
        float hp = hpart[idx];
        hpart[idx] = hrun;
        hrun = ap * hrun + hp;
    }
}

__global__ __launch_bounds__(256) void scan_emit_k(const bf16_t* __restrict__ dt,
                                                   const bf16_t* __restrict__ uc,
                                                   const float* __restrict__ xdbl,
                                                   const bf16_t* __restrict__ xz,
                                                   const float* __restrict__ A_log,
                                                   const float* __restrict__ Dp,
                                                   const float* __restrict__ hpart,
                                                   bf16_t* __restrict__ y) {
    int gid = blockIdx.x * 256 + threadIdx.x;
    if (gid >= B * NCH * DI) return;
    int d = gid % DI;
    int c = (gid / DI) % NCH;
    int b = gid / (DI * NCH);
    float Av[DS];
    {
        float4 a0 = *reinterpret_cast<const float4*>(A_log + d * DS);
        float4 a1 = *reinterpret_cast<const float4*>(A_log + d * DS + 4);
        Av[0] = -__expf(a0.x); Av[1] = -__expf(a0.y); Av[2] = -__expf(a0.z); Av[3] = -__expf(a0.w);
        Av[4] = -__expf(a1.x); Av[5] = -__expf(a1.y); Av[6] = -__expf(a1.z); Av[7] = -__expf(a1.w);
    }
    float h[DS];
    {
        size_t base = (((size_t)(b * NCH + c) * DI) + d) * DS;
        const f32x4* hp4 = reinterpret_cast<const f32x4*>(hpart + base);
        f32x4 v0 = hp4[0], v1 = hp4[1];
#pragma unroll
        for (int n = 0; n < 4; n++) { h[n] = v0[n]; h[n + 4] = v1[n]; }
    }
    float Dv = Dp[d];
    int l0 = c * CH;
    for (int t = 0; t < CH; t++) {
        size_t row = (size_t)b * L + l0 + t;
        float dtv = (float)dt[row * DI + d];
        float uv = (float)uc[row * DI + d];
        const float4* xr4 = reinterpret_cast<const float4*>(xdbl + row * XDW + DTR);
        float4 b0 = xr4[0], b1 = xr4[1], c0 = xr4[2], c1 = xr4[3];
        float Bv[DS] = {b0.x, b0.y, b0.z, b0.w, b1.x, b1.y, b1.z, b1.w};
        float Cv[DS] = {c0.x, c0.y, c0.z, c0.w, c1.x, c1.y, c1.z, c1.w};
        float du = dtv * uv;
        float yv = 0.f;
#pragma unroll
        for (int n = 0; n < DS; n++) {
            float dA = __expf(dtv * Av[n]);
            h[n] = dA * h[n] + du * Bv[n];
            yv += h[n] * Cv[n];
        }
        yv += uv * Dv;
        float zv = (float)xz[row * XZW + DI + d];
        yv *= zv / (1.0f + __expf(-zv));
        y[row * DI + d] = (bf16_t)yv;
    }
}

// ---------------- mean over L (2-stage), then head --------------------------
// partial layout: [b][c*4+rsub][DM]
__global__ __launch_bounds__(256) void mean_part_k(const bf16_t* __restrict__ hn,
                                                   float* __restrict__ partial) {
    int c = blockIdx.x;   // 32 chunks of 64 rows
    int b = blockIdx.y;
    int t = threadIdx.x;
    int d0 = (t & 63) * 8;
    int rsub = t >> 6;    // 4 row subsets
    float s[8] = {};
    for (int l = rsub; l < 64; l += 4) {
        bf16x8 v = *reinterpret_cast<const bf16x8*>(hn + (size_t)(b * L + c * 64 + l) * DM + d0);
#pragma unroll
        for (int j = 0; j < 8; j++) s[j] += (float)v[j];
    }
    float* dst = partial + ((size_t)(b * 32 + c) * 4 + rsub) * DM + d0;
    f32x4 o0, o1;
#pragma unroll
    for (int j = 0; j < 4; j++) { o0[j] = s[j]; o1[j] = s[j + 4]; }
    reinterpret_cast<f32x4*>(dst)[0] = o0;
    reinterpret_cast<f32x4*>(dst)[1] = o1;
}

__global__ void mean_fin_k(const float* __restrict__ partial, float* __restrict__ hmean) {
    int idx = blockIdx.x * blockDim.x + threadIdx.x;
    if (idx >= B * DM) return;
    int b = idx / DM, d = idx % DM;
    float s = 0.f;
    for (int c = 0; c < 128; c++) s += partial[((size_t)b * 128 + c) * DM + d];
    hmean[idx] = s * (1.0f / L);
}

__global__ void head_k(const float* __restrict__ hmean, const float* __restrict__ hw,
                       const float* __restrict__ hb, float* __restrict__ out) {
    int t = threadIdx.x;
    if (t >= B * NC) return;
    int b = t / NC, c = t % NC;
    float acc = hb[c];
    for (int k = 0; k < DM; k++) acc += hmean[b * DM + k] * hw[c * DM + k];
    out[t] = acc;
}

extern "C" void kernel_launch(void* const* d_in, const int* in_sizes, int n_in,
                              void* d_out, int out_size, void* d_ws, size_t ws_size,
                              hipStream_t stream) {
    const float* x      = (const float*)d_in[0];
    const float* inp_w  = (const float*)d_in[1];
    const float* inp_b  = (const float*)d_in[2];
    const float* norm_g = (const float*)d_in[3];
    const float* norm_b = (const float*)d_in[4];
    const float* in_w   = (const float*)d_in[5];
    const float* conv_w = (const float*)d_in[6];
    const float* conv_b = (const float*)d_in[7];
    const float* xp_w   = (const float*)d_in[8];
    const float* dt_w   = (const float*)d_in[9];
    const float* dt_b   = (const float*)d_in[10];
    const float* A_log  = (const float*)d_in[11];
    const float* Dp     = (const float*)d_in[12];
    const float* out_w  = (const float*)d_in[13];
    const float* fnorm_g = (const float*)d_in[14];
    const float* fnorm_b = (const float*)d_in[15];
    const float* head_w = (const float*)d_in[16];
    const float* head_b = (const float*)d_in[17];
    float* out = (float*)d_out;

    char* p = (char*)d_ws;
    float*  h     = (float*)p;  p += (size_t)M * DM * 4;
    bf16_t* hn    = (bf16_t*)p; p += (size_t)M * DM * 2;
    bf16_t* xz    = (bf16_t*)p; p += (size_t)M * XZW * 2;
    bf16_t* uc    = (bf16_t*)p; p += (size_t)M * DI * 2;
    float*  xdbl  = (float*)p;  p += (size_t)M * XDW * 4;
    bf16_t* xdt   = (bf16_t*)p; p += (size_t)M * DTR * 2;
    bf16_t* dtb   = (bf16_t*)p; p += (size_t)M * DI * 2;
    bf16_t* yb    = (bf16_t*)p; p += (size_t)M * DI * 2;
    float*  hpart = (float*)p;  p += (size_t)B * DI * NCH * DS * 4;
    float*  aprod = (float*)p;  p += (size_t)B * DI * NCH * DS * 4;
    float*  xpart = (float*)p;  p += (size_t)XSK * M * 64 * 4;
    float*  partial = (float*)p; p += (size_t)B * 128 * DM * 4;
    float*  hmean = (float*)p;  p += (size_t)B * DM * 4;
    bf16_t* wb_in = (bf16_t*)p; p += (size_t)NL * XZW * DM * 2;
    bf16_t* wb_xp = (bf16_t*)p; p += (size_t)NL * XPR * DI * 2;
    bf16_t* wb_dt = (bf16_t*)p; p += (size_t)NL * DI * DTR * 2;
    bf16_t* wb_out = (bf16_t*)p; p += (size_t)NL * DM * DI * 2;

    // weights -> bf16 (once per call; x_proj padded to 64 rows with zeros)
    cvt_ws_k<<<(WNTp + 255) / 256, 256, 0, stream>>>(in_w, xp_w, dt_w, out_w,
                                                     wb_in, wb_xp, wb_dt, wb_out);
    // embed + layer-0 LN fused
    embed_ln_k<<<M, 256, 0, stream>>>(x, inp_w, inp_b, norm_g, norm_b, h, hn);

    for (int i = 0; i < NL; i++) {
        const bf16_t* inw_i = wb_in + (size_t)i * XZW * DM;
        const float* cw_i  = conv_w + (size_t)i * DI * DC;
        const float* cb_i  = conv_b + (size_t)i * DI;
        const bf16_t* xpw_i = wb_xp + (size_t)i * XPR * DI;
        const bf16_t* dtw_i = wb_dt + (size_t)i * DI * DTR;
        const float* dtb_i = dt_b + (size_t)i * DI;
        const float* Al_i  = A_log + (size_t)i * DI * DS;
        const float* Dp_i  = Dp + (size_t)i * DI;
        const bf16_t* ow_i  = wb_out + (size_t)i * DM * DI;

        // hn = LN(h) -> bf16 (layer 0 already done by embed_ln_k)
        if (i > 0)
            layernorm_k<<<M, 256, 0, stream>>>(h, norm_g + i * DM, norm_b + i * DM, hn);
        // xz = hn @ in_w^T   (M x 2048, K=512), 128x128 tiles -> 1024 blocks
        gemm_mfma<128, 128, 0, bf16_t, 1><<<dim3(XZW / 128, M / 128), 256, 0, stream>>>(
            hn, DM, inw_i, DM, nullptr, xz, XZW, XZW, DM);
        // uc = silu(conv(u)), 8 ch/thread
        conv_silu_k<<<(M * DI / 8 + 255) / 256, 256, 0, stream>>>(xz, cw_i, cb_i, uc);
        // xdbl = uc @ xp_w^T  (M x 48, K=1024) split-K=8, BM=128 -> 512 blocks
        gemm_mfma<128, 64, 0, float, XSK><<<dim3(1, M / 128, XSK), 256, 0, stream>>>(
            uc, DI, xpw_i, DI, nullptr, xpart, 64, XDW, DI);
        xproj_reduce_k<<<(M * XDW + 255) / 256, 256, 0, stream>>>(xpart, xdbl, xdt);
        // dt = softplus(xdt @ dt_w^T + dt_b)  (M x 1024, K=32), 128x64 tiles
        gemm_mfma<128, 64, 2, bf16_t, 1><<<dim3(DI / 64, M / 128), 256, 0, stream>>>(
            xdt, DTR, dtw_i, DTR, dtb_i, dtb, DI, DI, DTR);
        // selective scan (chunked), fused gate + u*D
        scan_part_k<<<(B * NCH * DI) / 256, 256, 0, stream>>>(dtb, uc, xdbl, Al_i, hpart, aprod);
        scan_combine_k<<<(B * DI * DS + 255) / 256, 256, 0, stream>>>(hpart, aprod);
        scan_emit_k<<<(B * NCH * DI) / 256, 256, 0, stream>>>(dtb, uc, xdbl, xz, Al_i, Dp_i, hpart, yb);
        // h += y @ out_w^T  (M x 512, K=1024), 128x64 tiles -> 512 blocks
        gemm_mfma<128, 64, 1, float, 1><<<dim3(DM / 64, M / 128), 256, 0, stream>>>(
            yb, DI, ow_i, DI, nullptr, h, DM, DM, DI);
    }

    // final LN -> mean over L (2-stage) -> head
    layernorm_k<<<M, 256, 0, stream>>>(h, fnorm_g, fnorm_b, hn);
    mean_part_k<<<dim3(32, B), 256, 0, stream>>>(hn, partial);
    mean_fin_k<<<(B * DM + 255) / 256, 256, 0, stream>>>(partial, hmean);
    head_k<<<1, 256, 0, stream>>>(hmean, head_w, head_b, out);
}